// Round 9
// baseline (144.933 us; speedup 1.0000x reference)
//
#include <hip/hip_runtime.h>
#include <math.h>

#define NTOK 2304      // 48*48 tokens
#define BATCH 2
#define CIN 256
#define HID 512        // 8 heads * 64
#define NH 8
#define LOG2E 1.44269504088896340736f

typedef __attribute__((ext_vector_type(8))) short bfrag;    // 8 bf16 (4 VGPRs)
typedef __attribute__((ext_vector_type(16))) float f32x16;  // MFMA 32x32 accumulator

#if __has_builtin(__builtin_amdgcn_exp2f)
#define EXP2(x) __builtin_amdgcn_exp2f(x)
#else
#define EXP2(x) exp2f(x)
#endif

// fp32 -> bf16 (RNE)
__device__ __forceinline__ unsigned f2bf(float f) {
    unsigned u = __float_as_uint(f);
    u += 0x7FFF + ((u >> 16) & 1);
    return u >> 16;
}

__device__ __forceinline__ float bf2f(unsigned short s) {
    return __uint_as_float(((unsigned)s) << 16);
}

// pack trunc(hi(b)) , trunc(hi(a)) -> one dword {bf16(b):bf16(a)} in 1 v_perm
__device__ __forceinline__ unsigned pk_trunc(float a, float b) {
    return __builtin_amdgcn_perm(__float_as_uint(b), __float_as_uint(a), 0x07060302u);
}

// exp2 + bf16-pack + lane^32 half-swap: accS (S^T quadrant, C-layout) ->
// two A-operand P frags; accumulates this lane's partial row sums (tree).
__device__ __forceinline__ void softmax_frag(
    const f32x16& accS, int h, float& ps0, float& ps1, bfrag& P0, bfrag& P1)
{
    unsigned dw[8];
    float e0[8], e1[8];
#pragma unroll
    for (int i = 0; i < 8; i++) {
        float plo = EXP2(accS[2 * i]);
        float phi = EXP2(accS[2 * i + 1]);
        dw[i] = pk_trunc(plo, phi);
        e0[i] = __uint_as_float(dw[i] << 16);
        e1[i] = __uint_as_float(dw[i] & 0xffff0000u);
    }
    ps0 += ((e0[0] + e0[1]) + (e0[2] + e0[3])) + ((e0[4] + e0[5]) + (e0[6] + e0[7]));
    ps1 += ((e1[0] + e1[1]) + (e1[2] + e1[3])) + ((e1[4] + e1[5]) + (e1[6] + e1[7]));
    unsigned sa0 = h ? dw[0] : dw[2], sb0 = h ? dw[1] : dw[3];
    unsigned sa1 = h ? dw[4] : dw[6], sb1 = h ? dw[5] : dw[7];
    unsigned ra0 = (unsigned)__shfl_xor((int)sa0, 32, 64);
    unsigned rb0 = (unsigned)__shfl_xor((int)sb0, 32, 64);
    unsigned ra1 = (unsigned)__shfl_xor((int)sa1, 32, 64);
    unsigned rb1 = (unsigned)__shfl_xor((int)sb1, 32, 64);
    union { bfrag f; unsigned u[4]; } U0, U1;
    U0.u[0] = h ? ra0 : dw[0];  U0.u[1] = h ? rb0 : dw[1];
    U0.u[2] = h ? dw[2] : ra0;  U0.u[3] = h ? dw[3] : rb0;
    U1.u[0] = h ? ra1 : dw[4];  U1.u[1] = h ? rb1 : dw[5];
    U1.u[2] = h ? dw[6] : ra1;  U1.u[3] = h ? dw[7] : rb1;
    P0 = U0.f; P1 = U1.f;
}

// ---------------------------------------------------------------------------
// Merged input pack: weights (frag-major) + x transpose-pack (frag-major).
//   bid <  288 : pack_xT tile; bid >= 288 : weights (bid 288 zeroes sumsq)
// ---------------------------------------------------------------------------
__global__ __launch_bounds__(256) void pack_all(
    const float* __restrict__ wq, short* __restrict__ wqb,
    const float* __restrict__ wp, short* __restrict__ wpb,
    const float* __restrict__ x, short* __restrict__ xT,
    float* __restrict__ sumsq)
{
    int bid = blockIdx.x;
    if (bid < 288) {
        int n0 = (bid % 36) * 64, c0 = ((bid / 36) & 3) * 64, b = bid / 144;
        __shared__ float sT[64][65];
        int tid = threadIdx.x, lane = tid & 63, wv = tid >> 6;
        for (int c = wv; c < 64; c += 4)
            sT[c][lane] = x[((size_t)b * CIN + c0 + c) * NTOK + n0 + lane];
        __syncthreads();
        int n = tid >> 2, c4 = (tid & 3) * 16;
        unsigned buf[8];
#pragma unroll
        for (int i = 0; i < 8; i++)
            buf[i] = f2bf(sT[c4 + 2 * i][n]) | (f2bf(sT[c4 + 2 * i + 1][n]) << 16);
        int n_tok = n0 + n;
        int l31n = n & 31;
        short* dst = xT + (((size_t)b * 72 + (n_tok >> 5)) * 16 + ((c0 + c4) >> 4)) * 512;
        ((uint4*)(dst + (0 * 32 + l31n) * 8))[0] = make_uint4(buf[0], buf[1], buf[2], buf[3]);
        ((uint4*)(dst + (1 * 32 + l31n) * 8))[0] = make_uint4(buf[4], buf[5], buf[6], buf[7]);
    } else {
        if (bid == 288) {
            ((float4*)sumsq)[threadIdx.x * 2] = make_float4(0.f, 0.f, 0.f, 0.f);
            ((float4*)sumsq)[threadIdx.x * 2 + 1] = make_float4(0.f, 0.f, 0.f, 0.f);
        }
        int e = ((bid - 288) * 256 + threadIdx.x) * 8;
        const int NQ = 1536 * 256;
        const float* src; short* dst;
        if (e < NQ) {
            int row = e >> 8, c = e & 255;
            int off = (((row >> 5) * 16 + (c >> 4)) * 64 + ((c >> 3) & 1) * 32 + (row & 31)) * 8;
            src = wq + e; dst = wqb + off;
        } else {
            int e2 = e - NQ;
            int row = e2 >> 9, c = e2 & 511;
            int off = (((row >> 5) * 32 + (c >> 4)) * 64 + ((c >> 3) & 1) * 32 + (row & 31)) * 8;
            src = wp + e2; dst = wpb + off;
        }
        float4 v0 = ((const float4*)src)[0];
        float4 v1 = ((const float4*)src)[1];
        unsigned b0 = f2bf(v0.x) | (f2bf(v0.y) << 16);
        unsigned b1 = f2bf(v0.z) | (f2bf(v0.w) << 16);
        unsigned b2 = f2bf(v1.x) | (f2bf(v1.y) << 16);
        unsigned b3 = f2bf(v1.z) | (f2bf(v1.w) << 16);
        *((uint4*)dst) = make_uint4(b0, b1, b2, b3);
    }
}

// ---------------------------------------------------------------------------
// QKV GEMM (MFMA): BM=128, BN=128, K=256, all operands fragment-major.
// q,k rows -> unnormalized bf16 qkt frag-major via coalesced uint2 stores;
// v rows -> bf16 vb frag-major. grid (18, 12, 2). (R8 version, unchanged.)
// ---------------------------------------------------------------------------
__global__ __launch_bounds__(256, 2) void gemm_qkv(
    const short* __restrict__ A,     // wqb frag-major
    const short* __restrict__ B,     // xT frag-major
    short* __restrict__ qku,         // qkt buffer (unnormalized at this stage)
    short* __restrict__ vb)
{
    int b = blockIdx.z;
    int o0 = blockIdx.y * 128;
    int n0 = blockIdx.x * 128;
    int tid = threadIdx.x, wv = tid >> 6, lane = tid & 63;
    int h = lane >> 5, l31 = lane & 31;

    const short* pa = A + ((size_t)(o0 >> 5) * 16) * 512 + lane * 8;
    const short* pb = B + (((size_t)b * 72 + (n0 >> 5) + wv) * 16) * 512 + lane * 8;

    f32x16 acc[4];
#pragma unroll
    for (int rb = 0; rb < 4; rb++)
#pragma unroll
        for (int r = 0; r < 16; r++) acc[rb][r] = 0.f;

#pragma unroll 2
    for (int kc = 0; kc < 16; kc++) {
        bfrag a0 = *(const bfrag*)(pa + (size_t)(0 * 16 + kc) * 512);
        bfrag a1 = *(const bfrag*)(pa + (size_t)(1 * 16 + kc) * 512);
        bfrag a2 = *(const bfrag*)(pa + (size_t)(2 * 16 + kc) * 512);
        bfrag a3 = *(const bfrag*)(pa + (size_t)(3 * 16 + kc) * 512);
        bfrag bb = *(const bfrag*)(pb + (size_t)kc * 512);
        acc[0] = __builtin_amdgcn_mfma_f32_32x32x16_bf16(a0, bb, acc[0], 0, 0, 0);
        acc[1] = __builtin_amdgcn_mfma_f32_32x32x16_bf16(a1, bb, acc[1], 0, 0, 0);
        acc[2] = __builtin_amdgcn_mfma_f32_32x32x16_bf16(a2, bb, acc[2], 0, 0, 0);
        acc[3] = __builtin_amdgcn_mfma_f32_32x32x16_bf16(a3, bb, acc[3], 0, 0, 0);
    }

    int nn = n0 + wv * 32 + l31;
    if (o0 < 1024) {
        int sel = o0 >> 9;                       // constant per block
        short* Qb = qku + (size_t)sel * (16 * NTOK * 64);
        int oo = o0 & 511;                       // row base within sel
        int tl = nn & 31;
        size_t base_mb = (size_t)(nn >> 5) * 4;  // mb*4
#pragma unroll
        for (int rb = 0; rb < 4; rb++) {
            int hh2 = (oo + rb * 32) >> 6;
            int ihi = (rb & 1) * 2;
            short* Qbb = Qb + (size_t)(b * 8 + hh2) * (NTOK * 64);
#pragma unroll
            for (int q = 0; q < 4; q++) {
                int i = ihi + (q >> 1);
                unsigned lo = f2bf(acc[rb][4 * q])     | (f2bf(acc[rb][4 * q + 1]) << 16);
                unsigned hi = f2bf(acc[rb][4 * q + 2]) | (f2bf(acc[rb][4 * q + 3]) << 16);
                *(uint2*)(Qbb + (base_mb + i) * 512 + ((q & 1) * 32 + tl) * 8 + 4 * h)
                    = make_uint2(lo, hi);
            }
        }
    } else {
        // fragment-major V store
        short* V = vb + (size_t)b * 512 * NTOK;
        int ov = o0 - 1024;
        int mb = nn >> 5, jc = (nn >> 4) & 1, hv = (nn >> 3) & 1, e = nn & 7;
#pragma unroll
        for (int rb = 0; rb < 4; rb++)
#pragma unroll
            for (int r = 0; r < 16; r++) {
                int ml = (r & 3) + 8 * (r >> 2) + 4 * h;
                int row = ov + rb * 32 + ml;                 // 0..511
                int hh2 = row >> 6, dl = row & 63;
                int jr = dl >> 5, l31v = dl & 31;
                V[((((size_t)hh2 * 72 + mb) * 4 + jr * 2 + jc) * 64
                   + hv * 32 + l31v) * 8 + e] = (short)f2bf(acc[rb][r]);
            }
    }
}

// ---------------------------------------------------------------------------
// Per-row sum of squares from bf16 qkt (streaming). grid 1152 x 64.
// (unchanged from R8 — both q and k raw rows reduced.)
// ---------------------------------------------------------------------------
__global__ __launch_bounds__(64) void sumsq_qk(
    const short* __restrict__ qkt, float* __restrict__ sumsq)
{
    int bid = blockIdx.x;
    int mc = bid % 9;
    int rest = bid / 9;
    int i = rest & 3;
    int selbh = rest >> 2;                  // 0..31
    int lane = threadIdx.x;
    const short* p = qkt + (((size_t)selbh * 72 + mc * 8) * 4 + i) * 512 + lane * 8;
    float sq[8] = {0.f, 0.f, 0.f, 0.f, 0.f, 0.f, 0.f, 0.f};
#pragma unroll
    for (int m = 0; m < 8; m++) {
        bfrag v = *(const bfrag*)(p + (size_t)m * 2048);
#pragma unroll
        for (int e = 0; e < 8; e++) {
            float f = bf2f((unsigned short)v[e]);
            sq[e] += f * f;
        }
    }
#pragma unroll
    for (int off = 1; off <= 16; off <<= 1)
#pragma unroll
        for (int e = 0; e < 8; e++)
            sq[e] += __shfl_xor(sq[e], off, 64);
    if ((lane & 31) == 0) {
        int sel = selbh >> 4, bh = selbh & 15;
        int b = bh >> 3, hh = bh & 7, hsel = lane >> 5;
        int dbase = i * 16 + hsel * 8;
        float* dst = sumsq + b * 1024 + sel * 512 + hh * 64 + dbase;
#pragma unroll
        for (int e = 0; e < 8; e++) atomicAdd(dst + e, sq[e]);
    }
}

// ---------------------------------------------------------------------------
// Q-ONLY scale: since the L2 norms are per-(b,h,d) row and S = sum_d q*k,
// both inverse norms fold into Q:  q' = q * log2e * iq[d] * ik[d];
// K stays RAW in qkt. Halves the scaled data (4.7 MB r/w vs 18.9).
// grid 1152 x 256 (sel=0 slots only).
// ---------------------------------------------------------------------------
__global__ __launch_bounds__(256) void scale_q(
    short* __restrict__ qkt, const float* __restrict__ sumsq)
{
    int s = blockIdx.x * 256 + threadIdx.x;       // q frag slot, 0..294911
    int lane = s & 63;
    int rest = s >> 6;
    int fi = rest & 3;
    int bh = rest / 288;                          // 0..15
    int b = bh >> 3, hh = bh & 7;
    int d0 = fi * 16 + (lane >> 5) * 8;
    const float* sq = sumsq + b * 1024 + hh * 64 + d0;        // q rows
    const float* sk = sumsq + b * 1024 + 512 + hh * 64 + d0;  // k rows
    float4 q0 = ((const float4*)sq)[0], q1 = ((const float4*)sq)[1];
    float4 k0 = ((const float4*)sk)[0], k1 = ((const float4*)sk)[1];
    float i0 = LOG2E / (fmaxf(sqrtf(q0.x), 1e-12f) * fmaxf(sqrtf(k0.x), 1e-12f));
    float i1 = LOG2E / (fmaxf(sqrtf(q0.y), 1e-12f) * fmaxf(sqrtf(k0.y), 1e-12f));
    float i2 = LOG2E / (fmaxf(sqrtf(q0.z), 1e-12f) * fmaxf(sqrtf(k0.z), 1e-12f));
    float i3 = LOG2E / (fmaxf(sqrtf(q0.w), 1e-12f) * fmaxf(sqrtf(k0.w), 1e-12f));
    float i4 = LOG2E / (fmaxf(sqrtf(q1.x), 1e-12f) * fmaxf(sqrtf(k1.x), 1e-12f));
    float i5 = LOG2E / (fmaxf(sqrtf(q1.y), 1e-12f) * fmaxf(sqrtf(k1.y), 1e-12f));
    float i6 = LOG2E / (fmaxf(sqrtf(q1.z), 1e-12f) * fmaxf(sqrtf(k1.z), 1e-12f));
    float i7 = LOG2E / (fmaxf(sqrtf(q1.w), 1e-12f) * fmaxf(sqrtf(k1.w), 1e-12f));
    uint4 v = ((uint4*)qkt)[s];
    unsigned o0w = f2bf(__uint_as_float(v.x << 16) * i0)
                 | (f2bf(__uint_as_float(v.x & 0xffff0000u) * i1) << 16);
    unsigned o1w = f2bf(__uint_as_float(v.y << 16) * i2)
                 | (f2bf(__uint_as_float(v.y & 0xffff0000u) * i3) << 16);
    unsigned o2w = f2bf(__uint_as_float(v.z << 16) * i4)
                 | (f2bf(__uint_as_float(v.z & 0xffff0000u) * i5) << 16);
    unsigned o3w = f2bf(__uint_as_float(v.w << 16) * i6)
                 | (f2bf(__uint_as_float(v.w & 0xffff0000u) * i7) << 16);
    ((uint4*)qkt)[s] = make_uint4(o0w, o1w, o2w, o3w);
}

// ---------------------------------------------------------------------------
// Attention v2: LDS-staged K/V, block-shared.
// 256-thread blocks (4 fat waves, each owning n-groups nb0 and nb0+128);
// the block loads each iteration's K/V tile ONCE (reg-staged, double-
// buffered LDS, one barrier/iter): vector-load traffic /4 vs R6, and the
// staged load has a full compute phase to land -> latency hidden.
// Grid 576 = 9 ntiles x (16 bh x 4 ms); XCD: sharers differ by 64 (0 mod 8).
// Opart partials bf16 FRAGMENT-MAJOR (as R7/R8).
// ---------------------------------------------------------------------------
__global__ __launch_bounds__(256, 2) void attn_nb(
    const short* __restrict__ qkt,   // frag-major; q pre-scaled log2e*iq*ik, k RAW
    const short* __restrict__ vb,    // frag-major
    short* __restrict__ Opart,       // [4 split][2][72][32][64][8] bf16
    float* __restrict__ lsum)        // [4 split][16][2304] fp32
{
    int bid = blockIdx.x;
    int g = bid & 63;
    int bh = g >> 2, ms = g & 3;
    int ntile = bid >> 6;               // 0..8 (256 tokens each)
    int b = bh >> 3, hh = bh & 7;
    int tid = threadIdx.x, wv = tid >> 6, lane = tid & 63;
    int h = lane >> 5, l31 = lane & 31;
    int nb0 = ntile * 256 + wv * 32;
    int nb1 = nb0 + 128;
    int mb0 = ms * 18;                  // starting 32-token m-block

    __shared__ short kls[2][2048];
    __shared__ short vls[2][2048];

    const short* Qt = qkt + (size_t)bh * NTOK * 64;
    // per-wave slice of the block's K/V stage: wave wv loads frag wv (1KB each)
    const short* kp = qkt + (size_t)16 * NTOK * 64 + (size_t)bh * NTOK * 64
                    + ((size_t)mb0 * 4) * 512 + wv * 512 + lane * 8;
    const short* vp = vb + (((size_t)(b * 8 + hh) * 72 + mb0) * 4) * 512
                    + wv * 512 + lane * 8;

    bfrag bQ0[4], bQ1[4];
    {
        const short* q0 = Qt + ((size_t)(nb0 >> 5) * 4) * 512 + lane * 8;
        const short* q1 = Qt + ((size_t)(nb1 >> 5) * 4) * 512 + lane * 8;
#pragma unroll
        for (int i = 0; i < 4; i++) {
            bQ0[i] = *(const bfrag*)(q0 + i * 512);
            bQ1[i] = *(const bfrag*)(q1 + i * 512);
        }
    }

    f32x16 aL0, aH0, aL1, aH1;
#pragma unroll
    for (int r = 0; r < 16; r++) { aL0[r] = 0.f; aH0[r] = 0.f; aL1[r] = 0.f; aH1[r] = 0.f; }
    float s00 = 0.f, s01 = 0.f, s10 = 0.f, s11 = 0.f;

    // prologue: stage iter-0 tile into buffer 0
    {
        bfrag k0 = *(const bfrag*)kp;
        bfrag v0 = *(const bfrag*)vp;
        *(bfrag*)&kls[0][wv * 512 + lane * 8] = k0;
        *(bfrag*)&vls[0][wv * 512 + lane * 8] = v0;
    }
    __syncthreads();

    int cur = 0;
#pragma unroll 2
    for (int it = 0; it < 18; it++) {
        // issue next tile's loads early (reg-staged; written to LDS post-compute)
        bfrag nk, nv;
        if (it < 17) {
            kp += 2048; vp += 2048;
            nk = *(const bfrag*)kp;
            nv = *(const bfrag*)vp;
        }

        // read this iter's 8 frags from LDS (shared by all 4 waves)
        bfrag ck[4], cv[4];
#pragma unroll
        for (int i = 0; i < 4; i++) {
            ck[i] = *(const bfrag*)&kls[cur][i * 512 + lane * 8];
            cv[i] = *(const bfrag*)&vls[cur][i * 512 + lane * 8];
        }

        // ---- S^T for group 0, softmax, then group 1 (accS regs reused)
        bfrag P00, P01, P10, P11;
        {
            f32x16 accS;
#pragma unroll
            for (int r = 0; r < 16; r++) accS[r] = 0.f;
            accS = __builtin_amdgcn_mfma_f32_32x32x16_bf16(ck[0], bQ0[0], accS, 0, 0, 0);
            accS = __builtin_amdgcn_mfma_f32_32x32x16_bf16(ck[1], bQ0[1], accS, 0, 0, 0);
            accS = __builtin_amdgcn_mfma_f32_32x32x16_bf16(ck[2], bQ0[2], accS, 0, 0, 0);
            accS = __builtin_amdgcn_mfma_f32_32x32x16_bf16(ck[3], bQ0[3], accS, 0, 0, 0);
            softmax_frag(accS, h, s00, s01, P00, P01);
        }
        {
            f32x16 accS;
#pragma unroll
            for (int r = 0; r < 16; r++) accS[r] = 0.f;
            accS = __builtin_amdgcn_mfma_f32_32x32x16_bf16(ck[0], bQ1[0], accS, 0, 0, 0);
            accS = __builtin_amdgcn_mfma_f32_32x32x16_bf16(ck[1], bQ1[1], accS, 0, 0, 0);
            accS = __builtin_amdgcn_mfma_f32_32x32x16_bf16(ck[2], bQ1[2], accS, 0, 0, 0);
            accS = __builtin_amdgcn_mfma_f32_32x32x16_bf16(ck[3], bQ1[3], accS, 0, 0, 0);
            softmax_frag(accS, h, s10, s11, P10, P11);
        }
        // ---- O^T += P V (V frags shared across both n-groups)
        aL0 = __builtin_amdgcn_mfma_f32_32x32x16_bf16(P00, cv[0], aL0, 0, 0, 0);
        aL0 = __builtin_amdgcn_mfma_f32_32x32x16_bf16(P01, cv[1], aL0, 0, 0, 0);
        aH0 = __builtin_amdgcn_mfma_f32_32x32x16_bf16(P00, cv[2], aH0, 0, 0, 0);
        aH0 = __builtin_amdgcn_mfma_f32_32x32x16_bf16(P01, cv[3], aH0, 0, 0, 0);
        aL1 = __builtin_amdgcn_mfma_f32_32x32x16_bf16(P10, cv[0], aL1, 0, 0, 0);
        aL1 = __builtin_amdgcn_mfma_f32_32x32x16_bf16(P11, cv[1], aL1, 0, 0, 0);
        aH1 = __builtin_amdgcn_mfma_f32_32x32x16_bf16(P10, cv[2], aH1, 0, 0, 0);
        aH1 = __builtin_amdgcn_mfma_f32_32x32x16_bf16(P11, cv[3], aH1, 0, 0, 0);

        // publish next tile (writes to the buffer everyone finished reading
        // at the previous barrier), then barrier
        if (it < 17) {
            *(bfrag*)&kls[cur ^ 1][wv * 512 + lane * 8] = nk;
            *(bfrag*)&vls[cur ^ 1][wv * 512 + lane * 8] = nv;
        }
        __syncthreads();
        cur ^= 1;
    }

    // ---- row sums: fold partner half, direct store
    float p0 = s00 + s01;
    p0 += __shfl_xor(p0, 32, 64);
    float p1 = s10 + s11;
    p1 += __shfl_xor(p1, 32, 64);
    if (h == 0) {
        lsum[((size_t)ms * 16 + bh) * NTOK + nb0 + l31] = p0;
        lsum[((size_t)ms * 16 + bh) * NTOK + nb1 + l31] = p1;
    }

    // ---- O^T partial stores (bf16, FRAGMENT-MAJOR)
    short* Ob = Opart + ((size_t)ms * 2 + b) * (72 * 32 * 64 * 8);
    int nbs0 = nb0 >> 5, nbs1 = nb1 >> 5;
    int kcL = hh * 4 + (l31 >> 4);          // (k>>4) for aL (k = hh*64 + l31)
    int kcH = kcL + 2;                      // for aH (k = hh*64 + 32 + l31)
    int e = l31 & 7;
    int hs8 = ((l31 >> 3) & 1) * 32;
#pragma unroll
    for (int r = 0; r < 16; r++) {
        int ml = (r & 3) + 8 * (r >> 2) + 4 * h;
        int wi = hs8 + ml;                  // within-slot lane index
        Ob[(((size_t)nbs0 * 32 + kcL) * 64 + wi) * 8 + e] = (short)f2bf(aL0[r]);
        Ob[(((size_t)nbs0 * 32 + kcH) * 64 + wi) * 8 + e] = (short)f2bf(aH0[r]);
        Ob[(((size_t)nbs1 * 32 + kcL) * 64 + wi) * 8 + e] = (short)f2bf(aL1[r]);
        Ob[(((size_t)nbs1 * 32 + kcH) * 64 + wi) * 8 + e] = (short)f2bf(aH1[r]);
    }
}

// ---------------------------------------------------------------------------
// Combine four m-splits (bf16 frag-major partials), normalize, pack bf16 aoT
// FRAGMENT-MAJOR [b][nb=72][kc=32][lane=64][8]. Fully streaming.
// grid 1152 x 256.
// ---------------------------------------------------------------------------
__global__ __launch_bounds__(256) void combine(
    const short* __restrict__ Opart, const float* __restrict__ lsum,
    short* __restrict__ aoT)
{
    int s = blockIdx.x * 256 + threadIdx.x;       // 0..294911
    int lane = s & 63, kc = (s >> 6) & 31, nbb = s >> 11;   // nbb = b*72+nb
    int b = nbb >= 72 ? 1 : 0, nb = nbb - 72 * b;
    int l31 = lane & 31;
    int n = nb * 32 + l31;
    int hh = kc >> 2;                              // head = k/64
    float l = 0.f;
#pragma unroll
    for (int ms = 0; ms < 4; ms++)
        l += lsum[((size_t)ms * 16 + b * 8 + hh) * NTOK + n];
    float inv = 1.f / l;
    const size_t MS = 2ull * 72 * 32 * 64 * 8;     // shorts per split
    float a[8] = {0.f, 0.f, 0.f, 0.f, 0.f, 0.f, 0.f, 0.f};
#pragma unroll
    for (int ms = 0; ms < 4; ms++) {
        uint4 v = *(const uint4*)(Opart + (size_t)ms * MS + (size_t)s * 8);
        a[0] += __uint_as_float(v.x << 16);
        a[1] += __uint_as_float(v.x & 0xffff0000u);
        a[2] += __uint_as_float(v.y << 16);
        a[3] += __uint_as_float(v.y & 0xffff0000u);
        a[4] += __uint_as_float(v.z << 16);
        a[5] += __uint_as_float(v.z & 0xffff0000u);
        a[6] += __uint_as_float(v.w << 16);
        a[7] += __uint_as_float(v.w & 0xffff0000u);
    }
    unsigned b0 = f2bf(a[0] * inv) | (f2bf(a[1] * inv) << 16);
    unsigned b1 = f2bf(a[2] * inv) | (f2bf(a[3] * inv) << 16);
    unsigned b2 = f2bf(a[4] * inv) | (f2bf(a[5] * inv) << 16);
    unsigned b3 = f2bf(a[6] * inv) | (f2bf(a[7] * inv) << 16);
    *((uint4*)(aoT + (size_t)s * 8)) = make_uint4(b0, b1, b2, b3);
}

// ---------------------------------------------------------------------------
// Proj GEMM (MFMA, frag-major operands, direct store + bias). BM=64, BN=128,
// K=512. grid (18, 4, 2).
// ---------------------------------------------------------------------------
__global__ __launch_bounds__(256, 2) void gemm_proj(
    const short* __restrict__ A,     // wpb frag-major [ob=8][kc=32][64][8]
    const short* __restrict__ B,     // aoT frag-major [b][nb=72][kc=32][64][8]
    const float* __restrict__ bias, float* __restrict__ y)
{
    int b = blockIdx.z;
    int o0 = blockIdx.y * 64;
    int n0 = blockIdx.x * 128;
    int tid = threadIdx.x, wv = tid >> 6, lane = tid & 63;
    int h = lane >> 5, l31 = lane & 31;

    const short* pa = A + ((size_t)(o0 >> 5) * 32) * 512 + lane * 8;
    const short* pb = B + (((size_t)b * 72 + (n0 >> 5) + wv) * 32) * 512 + lane * 8;

    f32x16 acc0, acc1;
#pragma unroll
    for (int r = 0; r < 16; r++) { acc0[r] = 0.f; acc1[r] = 0.f; }

#pragma unroll 4
    for (int kc = 0; kc < 32; kc++) {
        bfrag a0 = *(const bfrag*)(pa + (size_t)kc * 512);
        bfrag a1 = *(const bfrag*)(pa + (size_t)(32 + kc) * 512);
        bfrag bb = *(const bfrag*)(pb + (size_t)kc * 512);
        acc0 = __builtin_amdgcn_mfma_f32_32x32x16_bf16(a0, bb, acc0, 0, 0, 0);
        acc1 = __builtin_amdgcn_mfma_f32_32x32x16_bf16(a1, bb, acc1, 0, 0, 0);
    }

    int nn = n0 + wv * 32 + l31;
#pragma unroll
    for (int r = 0; r < 16; r++) {
        int ml = (r & 3) + 8 * (r >> 2) + 4 * h;
        y[((size_t)b * CIN + o0 + ml) * NTOK + nn] = acc0[r] + bias[o0 + ml];
        y[((size_t)b * CIN + o0 + 32 + ml) * NTOK + nn] = acc1[r] + bias[o0 + 32 + ml];
    }
}

// ---------------------------------------------------------------------------
// Workspace (<= 36,446,208 B of 37,748,736):
//   [0, 18,874,368)           Opart bf16 frag-major [4][2][72][32][64][8]
//                                                          (k5 -> k6)
//   [18,874,368, 23,592,960)  vb bf16 frag-major         (k2 -> k5)
//   [23,592,960, 33,030,144)  qkt bf16 frag-major        (k2 -> k5; q scaled
//                              in place k4, k stays raw); aoT overlays (k6->k7)
//   [33,030,144, 33,620,000~) lsum fp32 [4][16][2304]    (k5 -> k6, over dead xT)
//   [33,030,144, 35,389,440)  xT bf16 frag-major          (k1 -> k2, dead at k5)
//   [35,389,440, 36,175,872)  wqb bf16 frag-major
//   [36,175,872, 36,438,016)  wpb bf16 frag-major
//   [36,438,016, 36,446,208)  sumsq fp32 [2048]          (k1 zero, k3 acc, k4 read)
// ---------------------------------------------------------------------------
extern "C" void kernel_launch(void* const* d_in, const int* in_sizes, int n_in,
                              void* d_out, int out_size, void* d_ws, size_t ws_size,
                              hipStream_t stream)
{
    const float* x      = (const float*)d_in[0];
    const float* w_qkv  = (const float*)d_in[1];
    const float* w_proj = (const float*)d_in[2];
    const float* b_proj = (const float*)d_in[3];
    float* y = (float*)d_out;

    short* Opart = (short*)d_ws;
    short* vb    = (short*)((char*)d_ws + 18874368);
    short* qkt   = (short*)((char*)d_ws + 23592960);
    short* aoT   = (short*)((char*)d_ws + 23592960);
    float* lsum  = (float*)((char*)d_ws + 33030144);
    short* xT    = (short*)((char*)d_ws + 33030144);
    short* wqb   = (short*)((char*)d_ws + 35389440);
    short* wpb   = (short*)((char*)d_ws + 36175872);
    float* sumsq = (float*)((char*)d_ws + 36438016);

    // k1: merged pack — xT tiles + weights + sumsq=0
    pack_all<<<544, 256, 0, stream>>>(w_qkv, wqb, w_proj, wpb, x, xT, sumsq);
    // k2: QKV GEMM -> unnormalized q,k bf16 frag-major; v frag-major
    gemm_qkv<<<dim3(NTOK / 128, 1536 / 128, BATCH), 256, 0, stream>>>(
        wqb, xT, qkt, vb);
    // k3: per-row sum of squares from bf16 qkt
    sumsq_qk<<<1152, 64, 0, stream>>>(qkt, sumsq);
    // k4: Q-only scale (folds iq*ik*log2e into q; k stays raw)
    scale_q<<<1152, 256, 0, stream>>>(qkt, sumsq);
    // k5: attention v2 — LDS-staged K/V, 576 x 256-thread blocks
    attn_nb<<<576, 256, 0, stream>>>(qkt, vb, Opart, lsum);
    // k6: combine 4 splits (streaming) -> aoT frag-major bf16 (over dead qkt)
    combine<<<1152, 256, 0, stream>>>(Opart, lsum, aoT);
    // k7: proj GEMM, frag-major operands, direct store + bias
    gemm_proj<<<dim3(NTOK / 128, CIN / 64, BATCH), 256, 0, stream>>>(
        wpb, aoT, b_proj, y);
}

// Round 10
// 141.862 us; speedup vs baseline: 1.0216x; 1.0216x over previous
//
#include <hip/hip_runtime.h>
#include <math.h>

#define NTOK 2304      // 48*48 tokens
#define BATCH 2
#define CIN 256
#define HID 512        // 8 heads * 64
#define NH 8
#define LOG2E 1.44269504088896340736f

typedef __attribute__((ext_vector_type(8))) short bfrag;    // 8 bf16 (4 VGPRs)
typedef __attribute__((ext_vector_type(16))) float f32x16;  // MFMA 32x32 accumulator

#if __has_builtin(__builtin_amdgcn_exp2f)
#define EXP2(x) __builtin_amdgcn_exp2f(x)
#else
#define EXP2(x) exp2f(x)
#endif

// fp32 -> bf16 (RNE)
__device__ __forceinline__ unsigned f2bf(float f) {
    unsigned u = __float_as_uint(f);
    u += 0x7FFF + ((u >> 16) & 1);
    return u >> 16;
}

__device__ __forceinline__ float bf2f(unsigned short s) {
    return __uint_as_float(((unsigned)s) << 16);
}

// pack trunc(hi(b)) , trunc(hi(a)) -> one dword {bf16(b):bf16(a)} in 1 v_perm
__device__ __forceinline__ unsigned pk_trunc(float a, float b) {
    return __builtin_amdgcn_perm(__float_as_uint(b), __float_as_uint(a), 0x07060302u);
}

// exp2 + bf16-pack + lane^32 half-swap: accS (S^T quadrant, C-layout) ->
// two A-operand P frags; accumulates this lane's partial row sums (tree).
__device__ __forceinline__ void softmax_frag(
    const f32x16& accS, int h, float& ps0, float& ps1, bfrag& P0, bfrag& P1)
{
    unsigned dw[8];
    float e0[8], e1[8];
#pragma unroll
    for (int i = 0; i < 8; i++) {
        float plo = EXP2(accS[2 * i]);
        float phi = EXP2(accS[2 * i + 1]);
        dw[i] = pk_trunc(plo, phi);
        e0[i] = __uint_as_float(dw[i] << 16);
        e1[i] = __uint_as_float(dw[i] & 0xffff0000u);
    }
    ps0 += ((e0[0] + e0[1]) + (e0[2] + e0[3])) + ((e0[4] + e0[5]) + (e0[6] + e0[7]));
    ps1 += ((e1[0] + e1[1]) + (e1[2] + e1[3])) + ((e1[4] + e1[5]) + (e1[6] + e1[7]));
    unsigned sa0 = h ? dw[0] : dw[2], sb0 = h ? dw[1] : dw[3];
    unsigned sa1 = h ? dw[4] : dw[6], sb1 = h ? dw[5] : dw[7];
    unsigned ra0 = (unsigned)__shfl_xor((int)sa0, 32, 64);
    unsigned rb0 = (unsigned)__shfl_xor((int)sb0, 32, 64);
    unsigned ra1 = (unsigned)__shfl_xor((int)sa1, 32, 64);
    unsigned rb1 = (unsigned)__shfl_xor((int)sb1, 32, 64);
    union { bfrag f; unsigned u[4]; } U0, U1;
    U0.u[0] = h ? ra0 : dw[0];  U0.u[1] = h ? rb0 : dw[1];
    U0.u[2] = h ? dw[2] : ra0;  U0.u[3] = h ? dw[3] : rb0;
    U1.u[0] = h ? ra1 : dw[4];  U1.u[1] = h ? rb1 : dw[5];
    U1.u[2] = h ? dw[6] : ra1;  U1.u[3] = h ? dw[7] : rb1;
    P0 = U0.f; P1 = U1.f;
}

// ---------------------------------------------------------------------------
// Merged input pack: weights (frag-major) + x transpose-pack (frag-major).
//   bid <  288 : pack_xT tile; bid >= 288 : weights (bid 288 zeroes sumsq)
// ---------------------------------------------------------------------------
__global__ __launch_bounds__(256) void pack_all(
    const float* __restrict__ wq, short* __restrict__ wqb,
    const float* __restrict__ wp, short* __restrict__ wpb,
    const float* __restrict__ x, short* __restrict__ xT,
    float* __restrict__ sumsq)
{
    int bid = blockIdx.x;
    if (bid < 288) {
        int n0 = (bid % 36) * 64, c0 = ((bid / 36) & 3) * 64, b = bid / 144;
        __shared__ float sT[64][65];
        int tid = threadIdx.x, lane = tid & 63, wv = tid >> 6;
        for (int c = wv; c < 64; c += 4)
            sT[c][lane] = x[((size_t)b * CIN + c0 + c) * NTOK + n0 + lane];
        __syncthreads();
        int n = tid >> 2, c4 = (tid & 3) * 16;
        unsigned buf[8];
#pragma unroll
        for (int i = 0; i < 8; i++)
            buf[i] = f2bf(sT[c4 + 2 * i][n]) | (f2bf(sT[c4 + 2 * i + 1][n]) << 16);
        int n_tok = n0 + n;
        int l31n = n & 31;
        short* dst = xT + (((size_t)b * 72 + (n_tok >> 5)) * 16 + ((c0 + c4) >> 4)) * 512;
        ((uint4*)(dst + (0 * 32 + l31n) * 8))[0] = make_uint4(buf[0], buf[1], buf[2], buf[3]);
        ((uint4*)(dst + (1 * 32 + l31n) * 8))[0] = make_uint4(buf[4], buf[5], buf[6], buf[7]);
    } else {
        if (bid == 288) {
            ((float4*)sumsq)[threadIdx.x * 2] = make_float4(0.f, 0.f, 0.f, 0.f);
            ((float4*)sumsq)[threadIdx.x * 2 + 1] = make_float4(0.f, 0.f, 0.f, 0.f);
        }
        int e = ((bid - 288) * 256 + threadIdx.x) * 8;
        const int NQ = 1536 * 256;
        const float* src; short* dst;
        if (e < NQ) {
            int row = e >> 8, c = e & 255;
            int off = (((row >> 5) * 16 + (c >> 4)) * 64 + ((c >> 3) & 1) * 32 + (row & 31)) * 8;
            src = wq + e; dst = wqb + off;
        } else {
            int e2 = e - NQ;
            int row = e2 >> 9, c = e2 & 511;
            int off = (((row >> 5) * 32 + (c >> 4)) * 64 + ((c >> 3) & 1) * 32 + (row & 31)) * 8;
            src = wp + e2; dst = wpb + off;
        }
        float4 v0 = ((const float4*)src)[0];
        float4 v1 = ((const float4*)src)[1];
        unsigned b0 = f2bf(v0.x) | (f2bf(v0.y) << 16);
        unsigned b1 = f2bf(v0.z) | (f2bf(v0.w) << 16);
        unsigned b2 = f2bf(v1.x) | (f2bf(v1.y) << 16);
        unsigned b3 = f2bf(v1.z) | (f2bf(v1.w) << 16);
        *((uint4*)dst) = make_uint4(b0, b1, b2, b3);
    }
}

// ---------------------------------------------------------------------------
// QKV GEMM (MFMA): BM=128, BN=128, K=256, all operands fragment-major.
// q,k rows -> unnormalized bf16 qkt frag-major via coalesced uint2 stores;
// v rows -> bf16 vb frag-major. grid (18, 12, 2). (unchanged from R8/R9.)
// ---------------------------------------------------------------------------
__global__ __launch_bounds__(256, 2) void gemm_qkv(
    const short* __restrict__ A,     // wqb frag-major
    const short* __restrict__ B,     // xT frag-major
    short* __restrict__ qku,         // qkt buffer (unnormalized at this stage)
    short* __restrict__ vb)
{
    int b = blockIdx.z;
    int o0 = blockIdx.y * 128;
    int n0 = blockIdx.x * 128;
    int tid = threadIdx.x, wv = tid >> 6, lane = tid & 63;
    int h = lane >> 5, l31 = lane & 31;

    const short* pa = A + ((size_t)(o0 >> 5) * 16) * 512 + lane * 8;
    const short* pb = B + (((size_t)b * 72 + (n0 >> 5) + wv) * 16) * 512 + lane * 8;

    f32x16 acc[4];
#pragma unroll
    for (int rb = 0; rb < 4; rb++)
#pragma unroll
        for (int r = 0; r < 16; r++) acc[rb][r] = 0.f;

#pragma unroll 2
    for (int kc = 0; kc < 16; kc++) {
        bfrag a0 = *(const bfrag*)(pa + (size_t)(0 * 16 + kc) * 512);
        bfrag a1 = *(const bfrag*)(pa + (size_t)(1 * 16 + kc) * 512);
        bfrag a2 = *(const bfrag*)(pa + (size_t)(2 * 16 + kc) * 512);
        bfrag a3 = *(const bfrag*)(pa + (size_t)(3 * 16 + kc) * 512);
        bfrag bb = *(const bfrag*)(pb + (size_t)kc * 512);
        acc[0] = __builtin_amdgcn_mfma_f32_32x32x16_bf16(a0, bb, acc[0], 0, 0, 0);
        acc[1] = __builtin_amdgcn_mfma_f32_32x32x16_bf16(a1, bb, acc[1], 0, 0, 0);
        acc[2] = __builtin_amdgcn_mfma_f32_32x32x16_bf16(a2, bb, acc[2], 0, 0, 0);
        acc[3] = __builtin_amdgcn_mfma_f32_32x32x16_bf16(a3, bb, acc[3], 0, 0, 0);
    }

    int nn = n0 + wv * 32 + l31;
    if (o0 < 1024) {
        int sel = o0 >> 9;                       // constant per block
        short* Qb = qku + (size_t)sel * (16 * NTOK * 64);
        int oo = o0 & 511;                       // row base within sel
        int tl = nn & 31;
        size_t base_mb = (size_t)(nn >> 5) * 4;  // mb*4
#pragma unroll
        for (int rb = 0; rb < 4; rb++) {
            int hh2 = (oo + rb * 32) >> 6;
            int ihi = (rb & 1) * 2;
            short* Qbb = Qb + (size_t)(b * 8 + hh2) * (NTOK * 64);
#pragma unroll
            for (int q = 0; q < 4; q++) {
                int i = ihi + (q >> 1);
                unsigned lo = f2bf(acc[rb][4 * q])     | (f2bf(acc[rb][4 * q + 1]) << 16);
                unsigned hi = f2bf(acc[rb][4 * q + 2]) | (f2bf(acc[rb][4 * q + 3]) << 16);
                *(uint2*)(Qbb + (base_mb + i) * 512 + ((q & 1) * 32 + tl) * 8 + 4 * h)
                    = make_uint2(lo, hi);
            }
        }
    } else {
        // fragment-major V store
        short* V = vb + (size_t)b * 512 * NTOK;
        int ov = o0 - 1024;
        int mb = nn >> 5, jc = (nn >> 4) & 1, hv = (nn >> 3) & 1, e = nn & 7;
#pragma unroll
        for (int rb = 0; rb < 4; rb++)
#pragma unroll
            for (int r = 0; r < 16; r++) {
                int ml = (r & 3) + 8 * (r >> 2) + 4 * h;
                int row = ov + rb * 32 + ml;                 // 0..511
                int hh2 = row >> 6, dl = row & 63;
                int jr = dl >> 5, l31v = dl & 31;
                V[((((size_t)hh2 * 72 + mb) * 4 + jr * 2 + jc) * 64
                   + hv * 32 + l31v) * 8 + e] = (short)f2bf(acc[rb][r]);
            }
    }
}

// ---------------------------------------------------------------------------
// Per-row sum of squares from bf16 qkt (streaming). grid 1152 x 64.
// ---------------------------------------------------------------------------
__global__ __launch_bounds__(64) void sumsq_qk(
    const short* __restrict__ qkt, float* __restrict__ sumsq)
{
    int bid = blockIdx.x;
    int mc = bid % 9;
    int rest = bid / 9;
    int i = rest & 3;
    int selbh = rest >> 2;                  // 0..31
    int lane = threadIdx.x;
    const short* p = qkt + (((size_t)selbh * 72 + mc * 8) * 4 + i) * 512 + lane * 8;
    float sq[8] = {0.f, 0.f, 0.f, 0.f, 0.f, 0.f, 0.f, 0.f};
#pragma unroll
    for (int m = 0; m < 8; m++) {
        bfrag v = *(const bfrag*)(p + (size_t)m * 2048);
#pragma unroll
        for (int e = 0; e < 8; e++) {
            float f = bf2f((unsigned short)v[e]);
            sq[e] += f * f;
        }
    }
#pragma unroll
    for (int off = 1; off <= 16; off <<= 1)
#pragma unroll
        for (int e = 0; e < 8; e++)
            sq[e] += __shfl_xor(sq[e], off, 64);
    if ((lane & 31) == 0) {
        int sel = selbh >> 4, bh = selbh & 15;
        int b = bh >> 3, hh = bh & 7, hsel = lane >> 5;
        int dbase = i * 16 + hsel * 8;
        float* dst = sumsq + b * 1024 + sel * 512 + hh * 64 + dbase;
#pragma unroll
        for (int e = 0; e < 8; e++) atomicAdd(dst + e, sq[e]);
    }
}

// ---------------------------------------------------------------------------
// Q-ONLY scale: both inverse norms + log2e fold into Q; K stays RAW.
// grid 1152 x 256. (unchanged from R9 — passed, absmax unchanged.)
// ---------------------------------------------------------------------------
__global__ __launch_bounds__(256) void scale_q(
    short* __restrict__ qkt, const float* __restrict__ sumsq)
{
    int s = blockIdx.x * 256 + threadIdx.x;       // q frag slot, 0..294911
    int lane = s & 63;
    int rest = s >> 6;
    int fi = rest & 3;
    int bh = rest / 288;                          // 0..15
    int b = bh >> 3, hh = bh & 7;
    int d0 = fi * 16 + (lane >> 5) * 8;
    const float* sq = sumsq + b * 1024 + hh * 64 + d0;        // q rows
    const float* sk = sumsq + b * 1024 + 512 + hh * 64 + d0;  // k rows
    float4 q0 = ((const float4*)sq)[0], q1 = ((const float4*)sq)[1];
    float4 k0 = ((const float4*)sk)[0], k1 = ((const float4*)sk)[1];
    float i0 = LOG2E / (fmaxf(sqrtf(q0.x), 1e-12f) * fmaxf(sqrtf(k0.x), 1e-12f));
    float i1 = LOG2E / (fmaxf(sqrtf(q0.y), 1e-12f) * fmaxf(sqrtf(k0.y), 1e-12f));
    float i2 = LOG2E / (fmaxf(sqrtf(q0.z), 1e-12f) * fmaxf(sqrtf(k0.z), 1e-12f));
    float i3 = LOG2E / (fmaxf(sqrtf(q0.w), 1e-12f) * fmaxf(sqrtf(k0.w), 1e-12f));
    float i4 = LOG2E / (fmaxf(sqrtf(q1.x), 1e-12f) * fmaxf(sqrtf(k1.x), 1e-12f));
    float i5 = LOG2E / (fmaxf(sqrtf(q1.y), 1e-12f) * fmaxf(sqrtf(k1.y), 1e-12f));
    float i6 = LOG2E / (fmaxf(sqrtf(q1.z), 1e-12f) * fmaxf(sqrtf(k1.z), 1e-12f));
    float i7 = LOG2E / (fmaxf(sqrtf(q1.w), 1e-12f) * fmaxf(sqrtf(k1.w), 1e-12f));
    uint4 v = ((uint4*)qkt)[s];
    unsigned o0w = f2bf(__uint_as_float(v.x << 16) * i0)
                 | (f2bf(__uint_as_float(v.x & 0xffff0000u) * i1) << 16);
    unsigned o1w = f2bf(__uint_as_float(v.y << 16) * i2)
                 | (f2bf(__uint_as_float(v.y & 0xffff0000u) * i3) << 16);
    unsigned o2w = f2bf(__uint_as_float(v.z << 16) * i4)
                 | (f2bf(__uint_as_float(v.z & 0xffff0000u) * i5) << 16);
    unsigned o3w = f2bf(__uint_as_float(v.w << 16) * i6)
                 | (f2bf(__uint_as_float(v.w & 0xffff0000u) * i7) << 16);
    ((uint4*)qkt)[s] = make_uint4(o0w, o1w, o2w, o3w);
}

// ---------------------------------------------------------------------------
// Attention v3: FINE-GRAIN GRID to kill dispatch quantization.
// Diagnosis: attn was pinned at ~44us across 5 structures because every
// config had grid/resident-slots in (1,2] -> 2 lockstep rounds of ~22us
// blocks. Fix: 1-wave (64-thread) blocks, grid 4608 = 64 (bh,ms) x 72 nb.
// Block time ~5us; slots ~4096 -> makespan ~2 small rounds. No barrier,
// no LDS; reg prefetch; R9 math (Q pre-folded, K raw); frag-major Opart.
// XCD decode: XCD x (bid&7) owns 8 (bh,ms) pairs with contiguous nb walk
// -> per-XCD K/V set ~1.2MB, L2-resident.
// ---------------------------------------------------------------------------
__global__ __launch_bounds__(64, 4) void attn_nb(
    const short* __restrict__ qkt,   // frag-major; q pre-scaled, k RAW
    const short* __restrict__ vb,    // frag-major
    short* __restrict__ Opart,       // [4 split][2][72][32][64][8] bf16
    float* __restrict__ lsum)        // [4 split][16][2304] fp32
{
    int bid = blockIdx.x;
    int x = bid & 7;                    // XCD under round-robin dispatch
    int r = bid >> 3;                   // 0..575
    int g = x * 8 + r / 72;             // (bh,ms) pair 0..63
    int nbi = r % 72;                   // 32-token n-group
    int bh = g >> 2, ms = g & 3;
    int b = bh >> 3, hh = bh & 7;
    int lane = threadIdx.x;
    int h = lane >> 5, l31 = lane & 31;
    int nb = nbi * 32;
    int mb0 = ms * 18;                  // starting 32-token m-block

    const short* Qt = qkt + (size_t)bh * NTOK * 64;
    const short* kp = qkt + (size_t)16 * NTOK * 64 + (size_t)bh * NTOK * 64
                    + ((size_t)mb0 * 4) * 512 + lane * 8;
    const short* vp = vb + (((size_t)(b * 8 + hh) * 72 + mb0) * 4) * 512 + lane * 8;

    bfrag bQ[4];
    {
        const short* q0 = Qt + ((size_t)nbi * 4) * 512 + lane * 8;
#pragma unroll
        for (int i = 0; i < 4; i++) bQ[i] = *(const bfrag*)(q0 + i * 512);
    }

    f32x16 aL, aH;
#pragma unroll
    for (int r2 = 0; r2 < 16; r2++) { aL[r2] = 0.f; aH[r2] = 0.f; }
    float s0 = 0.f, s1 = 0.f;

    // prologue: load iter-0 frags
    bfrag ck[4], cv[4];
#pragma unroll
    for (int i = 0; i < 4; i++) {
        ck[i] = *(const bfrag*)(kp + i * 512);
        cv[i] = *(const bfrag*)(vp + i * 512);
    }

#pragma unroll 2
    for (int it = 0; it < 18; it++) {
        // prefetch iter t+1 (final iter reads one 4KB tile past this bh's
        // section; still inside the allocated workspace -> safe, unused)
        kp += 2048; vp += 2048;
        bfrag nk[4], nv[4];
#pragma unroll
        for (int i = 0; i < 4; i++) {
            nk[i] = *(const bfrag*)(kp + i * 512);
            nv[i] = *(const bfrag*)(vp + i * 512);
        }

        // ---- S^T, softmax -> P frags
        bfrag P0, P1;
        {
            f32x16 accS;
#pragma unroll
            for (int r2 = 0; r2 < 16; r2++) accS[r2] = 0.f;
            accS = __builtin_amdgcn_mfma_f32_32x32x16_bf16(ck[0], bQ[0], accS, 0, 0, 0);
            accS = __builtin_amdgcn_mfma_f32_32x32x16_bf16(ck[1], bQ[1], accS, 0, 0, 0);
            accS = __builtin_amdgcn_mfma_f32_32x32x16_bf16(ck[2], bQ[2], accS, 0, 0, 0);
            accS = __builtin_amdgcn_mfma_f32_32x32x16_bf16(ck[3], bQ[3], accS, 0, 0, 0);
            softmax_frag(accS, h, s0, s1, P0, P1);
        }
        // ---- O^T += P V
        aL = __builtin_amdgcn_mfma_f32_32x32x16_bf16(P0, cv[0], aL, 0, 0, 0);
        aL = __builtin_amdgcn_mfma_f32_32x32x16_bf16(P1, cv[1], aL, 0, 0, 0);
        aH = __builtin_amdgcn_mfma_f32_32x32x16_bf16(P0, cv[2], aH, 0, 0, 0);
        aH = __builtin_amdgcn_mfma_f32_32x32x16_bf16(P1, cv[3], aH, 0, 0, 0);

        // rotate prefetched frags into current (renamed away by unroll)
#pragma unroll
        for (int i = 0; i < 4; i++) { ck[i] = nk[i]; cv[i] = nv[i]; }
    }

    // ---- row sum: fold partner half, direct store
    float p0 = s0 + s1;
    p0 += __shfl_xor(p0, 32, 64);
    if (h == 0)
        lsum[((size_t)ms * 16 + bh) * NTOK + nb + l31] = p0;

    // ---- O^T partial stores (bf16, FRAGMENT-MAJOR)
    short* Ob = Opart + ((size_t)ms * 2 + b) * (72 * 32 * 64 * 8);
    int kcL = hh * 4 + (l31 >> 4);          // (k>>4) for aL (k = hh*64 + l31)
    int kcH = kcL + 2;                      // for aH (k = hh*64 + 32 + l31)
    int e = l31 & 7;
    int hs8 = ((l31 >> 3) & 1) * 32;
#pragma unroll
    for (int r2 = 0; r2 < 16; r2++) {
        int ml = (r2 & 3) + 8 * (r2 >> 2) + 4 * h;
        int wi = hs8 + ml;                  // within-slot lane index
        Ob[(((size_t)nbi * 32 + kcL) * 64 + wi) * 8 + e] = (short)f2bf(aL[r2]);
        Ob[(((size_t)nbi * 32 + kcH) * 64 + wi) * 8 + e] = (short)f2bf(aH[r2]);
    }
}

// ---------------------------------------------------------------------------
// Combine four m-splits (bf16 frag-major partials), normalize, pack bf16 aoT
// FRAGMENT-MAJOR [b][nb=72][kc=32][lane=64][8]. Fully streaming.
// grid 1152 x 256.
// ---------------------------------------------------------------------------
__global__ __launch_bounds__(256) void combine(
    const short* __restrict__ Opart, const float* __restrict__ lsum,
    short* __restrict__ aoT)
{
    int s = blockIdx.x * 256 + threadIdx.x;       // 0..294911
    int lane = s & 63, kc = (s >> 6) & 31, nbb = s >> 11;   // nbb = b*72+nb
    int b = nbb >= 72 ? 1 : 0, nb = nbb - 72 * b;
    int l31 = lane & 31;
    int n = nb * 32 + l31;
    int hh = kc >> 2;                              // head = k/64
    float l = 0.f;
#pragma unroll
    for (int ms = 0; ms < 4; ms++)
        l += lsum[((size_t)ms * 16 + b * 8 + hh) * NTOK + n];
    float inv = 1.f / l;
    const size_t MS = 2ull * 72 * 32 * 64 * 8;     // shorts per split
    float a[8] = {0.f, 0.f, 0.f, 0.f, 0.f, 0.f, 0.f, 0.f};
#pragma unroll
    for (int ms = 0; ms < 4; ms++) {
        uint4 v = *(const uint4*)(Opart + (size_t)ms * MS + (size_t)s * 8);
        a[0] += __uint_as_float(v.x << 16);
        a[1] += __uint_as_float(v.x & 0xffff0000u);
        a[2] += __uint_as_float(v.y << 16);
        a[3] += __uint_as_float(v.y & 0xffff0000u);
        a[4] += __uint_as_float(v.z << 16);
        a[5] += __uint_as_float(v.z & 0xffff0000u);
        a[6] += __uint_as_float(v.w << 16);
        a[7] += __uint_as_float(v.w & 0xffff0000u);
    }
    unsigned b0 = f2bf(a[0] * inv) | (f2bf(a[1] * inv) << 16);
    unsigned b1 = f2bf(a[2] * inv) | (f2bf(a[3] * inv) << 16);
    unsigned b2 = f2bf(a[4] * inv) | (f2bf(a[5] * inv) << 16);
    unsigned b3 = f2bf(a[6] * inv) | (f2bf(a[7] * inv) << 16);
    *((uint4*)(aoT + (size_t)s * 8)) = make_uint4(b0, b1, b2, b3);
}

// ---------------------------------------------------------------------------
// Proj GEMM (MFMA, frag-major operands, direct store + bias). BM=64, BN=128,
// K=512. grid (18, 4, 2).
// ---------------------------------------------------------------------------
__global__ __launch_bounds__(256, 2) void gemm_proj(
    const short* __restrict__ A,     // wpb frag-major [ob=8][kc=32][64][8]
    const short* __restrict__ B,     // aoT frag-major [b][nb=72][kc=32][64][8]
    const float* __restrict__ bias, float* __restrict__ y)
{
    int b = blockIdx.z;
    int o0 = blockIdx.y * 64;
    int n0 = blockIdx.x * 128;
    int tid = threadIdx.x, wv = tid >> 6, lane = tid & 63;
    int h = lane >> 5, l31 = lane & 31;

    const short* pa = A + ((size_t)(o0 >> 5) * 32) * 512 + lane * 8;
    const short* pb = B + (((size_t)b * 72 + (n0 >> 5) + wv) * 32) * 512 + lane * 8;

    f32x16 acc0, acc1;
#pragma unroll
    for (int r = 0; r < 16; r++) { acc0[r] = 0.f; acc1[r] = 0.f; }

#pragma unroll 4
    for (int kc = 0; kc < 32; kc++) {
        bfrag a0 = *(const bfrag*)(pa + (size_t)kc * 512);
        bfrag a1 = *(const bfrag*)(pa + (size_t)(32 + kc) * 512);
        bfrag bb = *(const bfrag*)(pb + (size_t)kc * 512);
        acc0 = __builtin_amdgcn_mfma_f32_32x32x16_bf16(a0, bb, acc0, 0, 0, 0);
        acc1 = __builtin_amdgcn_mfma_f32_32x32x16_bf16(a1, bb, acc1, 0, 0, 0);
    }

    int nn = n0 + wv * 32 + l31;
#pragma unroll
    for (int r = 0; r < 16; r++) {
        int ml = (r & 3) + 8 * (r >> 2) + 4 * h;
        y[((size_t)b * CIN + o0 + ml) * NTOK + nn] = acc0[r] + bias[o0 + ml];
        y[((size_t)b * CIN + o0 + 32 + ml) * NTOK + nn] = acc1[r] + bias[o0 + 32 + ml];
    }
}

// ---------------------------------------------------------------------------
// Workspace (<= 36,446,208 B of 37,748,736):
//   [0, 18,874,368)           Opart bf16 frag-major [4][2][72][32][64][8]
//                                                          (k5 -> k6)
//   [18,874,368, 23,592,960)  vb bf16 frag-major         (k2 -> k5)
//   [23,592,960, 33,030,144)  qkt bf16 frag-major        (k2 -> k5; q scaled
//                              in place k4, k stays raw); aoT overlays (k6->k7)
//   [33,030,144, 33,620,000~) lsum fp32 [4][16][2304]    (k5 -> k6, over dead xT)
//   [33,030,144, 35,389,440)  xT bf16 frag-major          (k1 -> k2, dead at k5)
//   [35,389,440, 36,175,872)  wqb bf16 frag-major
//   [36,175,872, 36,438,016)  wpb bf16 frag-major
//   [36,438,016, 36,446,208)  sumsq fp32 [2048]          (k1 zero, k3 acc, k4 read)
// ---------------------------------------------------------------------------
extern "C" void kernel_launch(void* const* d_in, const int* in_sizes, int n_in,
                              void* d_out, int out_size, void* d_ws, size_t ws_size,
                              hipStream_t stream)
{
    const float* x      = (const float*)d_in[0];
    const float* w_qkv  = (const float*)d_in[1];
    const float* w_proj = (const float*)d_in[2];
    const float* b_proj = (const float*)d_in[3];
    float* y = (float*)d_out;

    short* Opart = (short*)d_ws;
    short* vb    = (short*)((char*)d_ws + 18874368);
    short* qkt   = (short*)((char*)d_ws + 23592960);
    short* aoT   = (short*)((char*)d_ws + 23592960);
    float* lsum  = (float*)((char*)d_ws + 33030144);
    short* xT    = (short*)((char*)d_ws + 33030144);
    short* wqb   = (short*)((char*)d_ws + 35389440);
    short* wpb   = (short*)((char*)d_ws + 36175872);
    float* sumsq = (float*)((char*)d_ws + 36438016);

    // k1: merged pack — xT tiles + weights + sumsq=0
    pack_all<<<544, 256, 0, stream>>>(w_qkv, wqb, w_proj, wpb, x, xT, sumsq);
    // k2: QKV GEMM -> unnormalized q,k bf16 frag-major; v frag-major
    gemm_qkv<<<dim3(NTOK / 128, 1536 / 128, BATCH), 256, 0, stream>>>(
        wqb, xT, qkt, vb);
    // k3: per-row sum of squares from bf16 qkt
    sumsq_qk<<<1152, 64, 0, stream>>>(qkt, sumsq);
    // k4: Q-only scale (folds iq*ik*log2e into q; k stays raw)
    scale_q<<<1152, 256, 0, stream>>>(qkt, sumsq);
    // k5: attention v3 — 4608 x 1-wave blocks (fine-grain grid, no barrier)
    attn_nb<<<4608, 64, 0, stream>>>(qkt, vb, Opart, lsum);
    // k6: combine 4 splits (streaming) -> aoT frag-major bf16 (over dead qkt)
    combine<<<1152, 256, 0, stream>>>(Opart, lsum, aoT);
    // k7: proj GEMM, frag-major operands, direct store + bias
    gemm_proj<<<dim3(NTOK / 128, CIN / 64, BATCH), 256, 0, stream>>>(
        wpb, aoT, b_proj, y);
}